// Round 10
// baseline (38.962 us; speedup 1.0000x reference)
//
#include <hip/hip_runtime.h>
#include <math.h>

#define RPAD  24                 // row capacity (span guarantee <= 22), 8-row chunks
#define PLANE (RPAD * 32)        // 768 floats = 3 KB per channel plane
// r9 structure, ONE change: __syncthreads() REMOVED. Since r9 dropped the
// shared coord tables, each wave's LDS planes are wave-private (written by its
// own global_load_lds, read only by itself) -> its own vmcnt(0) suffices and
// the block-wide barrier only lockstepped 4 waves on the slowest DMA return.
// DMA global_load_lds (w=16) into LINEAR LDS; bank swizzle applied on the
// GLOBAL source group: LDS[yr][q] = G[srow][(q-yr)&7]; reads use (xg+yr)&7.
// LDS: 8 planes x 3 KB = 24 KB -> 6 blocks/CU (24 waves/CU).

typedef __attribute__((address_space(1))) const void gptr_t;
typedef __attribute__((address_space(3))) void lptr_t;

__global__ __launch_bounds__(256, 6) void roialign_kernel(
    const float* __restrict__ feat, const float* __restrict__ bbox,
    float* __restrict__ out) {
  __shared__ float lds[8 * PLANE];

  const int blk = blockIdx.x;
  const int n  = blk >> 5;                   // 32 chunks of 8 channels per box
  const int c0 = (blk & 31) * 8;
  const int t  = threadIdx.x;
  const int wv = t >> 6;                     // wave owns channels c0+2wv, +1
  const int ln = t & 63;

  const float bx1 = bbox[n * 4 + 0];
  const float by1 = bbox[n * 4 + 1];
  const float bx2 = bbox[n * 4 + 2];
  const float by2 = bbox[n * 4 + 3];
  const float xstep = (bx2 - bx1) * (1.0f / 14.0f);
  const float ystep = (by2 - by1) * (1.0f / 14.0f);

  // ---- row range touched by the 14 y samples (block-uniform) ----
  const int ylo = min(max((int)floorf(by1), 0), 31);
  const float ys13 = by1 + 13.0f * ystep;
  int yhi = min(min(max((int)floorf(ys13), 0), 31) + 1, 31);
  yhi = min(yhi, ylo + (RPAD - 1));          // defensive: never overflow LDS
  const int R = yhi - ylo + 1;               // rows needed (<= 22)

  // ---- DMA staging: wave wv stages channels 2wv and 2wv+1 ----
  {
    const float* srcA =
        feat + ((size_t)n * 256 + c0 + 2 * wv) * 1024 + (size_t)ylo * 32;
    float* dstA = lds + 2 * wv * PLANE;
    const int rch = ln >> 3;                 // row within 8-row chunk
    const int q   = ln & 7;                  // dest float4 group
    for (int it = 0; it * 8 < R; ++it) {     // wave-uniform trip count
      int yr   = it * 8 + rch;               // dest row
      int srow = min(yr, R - 1);             // clamp tail rows (dup fetch, L1 hit)
      int qp   = (q - yr) & 7;               // pre-swizzled source group
      const float* gpA = srcA + srow * 32 + qp * 4;
      lptr_t* lpA = (lptr_t*)(dstA + it * 256);         // wave-uniform dest
      __builtin_amdgcn_global_load_lds((gptr_t*)gpA, lpA, 16, 0, 0);
      const float* gpB = gpA + 1024;
      lptr_t* lpB = (lptr_t*)(dstA + PLANE + it * 256);
      __builtin_amdgcn_global_load_lds((gptr_t*)gpB, lpB, 16, 0, 0);
    }
  }
  asm volatile("s_waitcnt vmcnt(0)" ::: "memory");
  // NO __syncthreads(): planes are wave-private, own vmcnt(0) is sufficient.

  // ---- compute: lane s<49 -> one output of each of the wave's 2 channels ----
  if (ln < 49) {
    const int sy = ln / 7;                   // const divisor -> magic mul
    const int sx = ln - sy * 7;

    // per-lane coordinates in registers (formulas identical to r8's tables)
    int   xgv0[2], xlv0[2], xgv1[2], xlv1[2];
    float wxv[2];
    int   yr0v[2], yr1v[2];
    float wyv[2];
#pragma unroll
    for (int j = 0; j < 2; ++j) {
      float xs = bx1 + (float)(2 * sx + j) * xstep;
      float x0 = fminf(fmaxf(floorf(xs), 0.0f), 31.0f);
      int x0i = (int)x0;
      int x1i = min(x0i + 1, 31);
      xgv0[j] = x0i >> 2;
      xlv0[j] = x0i & 3;
      xgv1[j] = x1i >> 2;
      xlv1[j] = x1i & 3;
      wxv[j]  = xs - x0;
    }
#pragma unroll
    for (int i = 0; i < 2; ++i) {
      float yv = by1 + (float)(2 * sy + i) * ystep;
      float y0 = fminf(fmaxf(floorf(yv), 0.0f), 31.0f);
      int y0i = (int)y0;
      int y1i = min(y0i + 1, 31);
      y0i = min(max(y0i, ylo), yhi);         // stays within staged span
      y1i = min(max(y1i, ylo), yhi);
      yr0v[i] = y0i - ylo;                   // row index within staged span
      yr1v[i] = y1i - ylo;
      wyv[i]  = yv - y0;
    }

    const float* plane = lds + 2 * wv * PLANE;  // channel A; B at +PLANE
    float mA = -INFINITY, mB = -INFINITY;
#pragma unroll
    for (int i = 0; i < 2; ++i) {
      const int yr0 = yr0v[i];
      const int yr1 = yr1v[i];
      const float wy = wyv[i];
      const float* r0 = plane + yr0 * 32;
      const float* r1 = plane + yr1 * 32;
#pragma unroll
      for (int j = 0; j < 2; ++j) {
        const int xg0 = xgv0[j], xl0 = xlv0[j];
        const int xg1 = xgv1[j], xl1 = xlv1[j];
        const float wx = wxv[j];
        const int o00 = (((xg0 + yr0) & 7) << 2) + xl0;
        const int o01 = (((xg1 + yr0) & 7) << 2) + xl1;
        const int o10 = (((xg0 + yr1) & 7) << 2) + xl0;
        const int o11 = (((xg1 + yr1) & 7) << 2) + xl1;
        float vA00 = r0[o00], vB00 = r0[o00 + PLANE];   // B: offset:3072 imm
        float vA01 = r0[o01], vB01 = r0[o01 + PLANE];
        float vA10 = r1[o10], vB10 = r1[o10 + PLANE];
        float vA11 = r1[o11], vB11 = r1[o11 + PLANE];
        float tA = fmaf(wx, vA01 - vA00, vA00);
        float bA = fmaf(wx, vA11 - vA10, vA10);
        mA = fmaxf(mA, fmaf(wy, bA - tA, tA));
        float tB = fmaf(wx, vB01 - vB00, vB00);
        float bB = fmaf(wx, vB11 - vB10, vB10);
        mB = fmaxf(mB, fmaf(wy, bB - tB, tB));
      }
    }
    float* op = out + ((size_t)n * 256 + c0 + 2 * wv) * 49 + ln;
    op[0]  = mA;
    op[49] = mB;
  }
}

extern "C" void kernel_launch(void* const* d_in, const int* in_sizes, int n_in,
                              void* d_out, int out_size, void* d_ws, size_t ws_size,
                              hipStream_t stream) {
  const float* feat = (const float*)d_in[0];
  const float* bbox = (const float*)d_in[1];
  float* out = (float*)d_out;
  dim3 grid(512 * 32);                       // one block per (box, 8-channel group)
  roialign_kernel<<<grid, 256, 0, stream>>>(feat, bbox, out);
}